// Round 1
// baseline (649.115 us; speedup 1.0000x reference)
//
#include <hip/hip_runtime.h>
#include <math.h>

#define BB 4
#define CC 256
#define HWN 4096

// ---------------------------------------------------------------------------
// Projection: Qt[b][d][n] = sum_c w[d][c] * F[b][c][n] + bias[d]
// d-major output so the scores GEMM reads both operands coalesced along n.
// Block: 64(n) x 64(d) tile, 256 threads, 4x4 register tile, LDS staging.
// ---------------------------------------------------------------------------
__global__ __launch_bounds__(256) void proj_kernel(
    const float* __restrict__ feature,
    const float* __restrict__ q_w, const float* __restrict__ q_b,
    const float* __restrict__ k_w, const float* __restrict__ k_b,
    float* __restrict__ qt, float* __restrict__ kt)
{
    int id = blockIdx.x;
    int dtile = id & 3;  id >>= 2;
    int ntile = id & 63; id >>= 6;
    int which = id & 1;  id >>= 1;
    int b = id;

    const float* w    = which ? k_w : q_w;
    const float* bias = which ? k_b : q_b;
    float* outp       = which ? kt  : qt;

    int n0 = ntile * 64, d0 = dtile * 64;
    const float* F = feature + (size_t)b * CC * HWN;

    __shared__ __align__(16) float lw[16][68];  // [c][d]
    __shared__ __align__(16) float lf[16][68];  // [c][n]

    int t  = threadIdx.x;
    int tx = t & 15, ty = t >> 4;

    float acc[4][4];
    #pragma unroll
    for (int i = 0; i < 4; i++)
        #pragma unroll
        for (int j = 0; j < 4; j++) acc[i][j] = 0.f;

    for (int c0 = 0; c0 < CC; c0 += 16) {
        // stage W tile transposed: lw[cc][dd] = w[(d0+dd)*C + c0+cc]
        {
            int cc = t & 15, dd0 = t >> 4;
            #pragma unroll
            for (int r = 0; r < 4; r++) {
                int dd = dd0 + 16 * r;
                lw[cc][dd] = w[(size_t)(d0 + dd) * CC + c0 + cc];
            }
        }
        // stage F tile: lf[cc][nn] = F[(c0+cc)*HW + n0+nn]  (coalesced)
        {
            int nn = t & 63, cc0 = t >> 6;
            #pragma unroll
            for (int r = 0; r < 4; r++) {
                int cc = cc0 + 4 * r;
                lf[cc][nn] = F[(size_t)(c0 + cc) * HWN + n0 + nn];
            }
        }
        __syncthreads();
        #pragma unroll
        for (int cc = 0; cc < 16; cc++) {
            float4 wv4 = *(const float4*)&lw[cc][4 * ty];
            float4 fv4 = *(const float4*)&lf[cc][4 * tx];
            float wv[4] = {wv4.x, wv4.y, wv4.z, wv4.w};
            float fv[4] = {fv4.x, fv4.y, fv4.z, fv4.w};
            #pragma unroll
            for (int i = 0; i < 4; i++)
                #pragma unroll
                for (int j = 0; j < 4; j++)
                    acc[i][j] = fmaf(wv[i], fv[j], acc[i][j]);
        }
        __syncthreads();
    }

    #pragma unroll
    for (int i = 0; i < 4; i++) {
        float bi = bias[d0 + 4 * ty + i];
        float4 o = make_float4(acc[i][0] + bi, acc[i][1] + bi,
                               acc[i][2] + bi, acc[i][3] + bi);
        *(float4*)&outp[(size_t)b * CC * HWN + (size_t)(d0 + 4 * ty + i) * HWN
                        + n0 + 4 * tx] = o;
    }
}

// ---------------------------------------------------------------------------
// Attention: block = (batch, 64-query tile, 1024-key range).
// No max-subtraction (scores bounded ~ +-5): num/den are plain sums ->
// key-range split with atomicAdd partials is exact.
// ---------------------------------------------------------------------------
__global__ __launch_bounds__(256) void attn_kernel(
    const float* __restrict__ qt, const float* __restrict__ kt,
    const float* __restrict__ flow,
    float* __restrict__ den_g, float* __restrict__ nx_g, float* __restrict__ ny_g)
{
    int id = blockIdx.x;
    int sr    = id & 3;  id >>= 2;
    int qtile = id & 63; id >>= 6;
    int b = id;

    int q0 = qtile * 64;
    int s_beg = sr * 1024;

    const float* Q  = qt + (size_t)b * CC * HWN;
    const float* K  = kt + (size_t)b * CC * HWN;
    const float* fx = flow + (size_t)b * 2 * HWN;
    const float* fy = fx + HWN;

    __shared__ __align__(16) float lq[16][68];  // [d][q]
    __shared__ __align__(16) float lk[16][68];  // [d][s]

    int t  = threadIdx.x;
    int tx = t & 15, ty = t >> 4;

    float den[4] = {0.f, 0.f, 0.f, 0.f};
    float nx[4]  = {0.f, 0.f, 0.f, 0.f};
    float ny[4]  = {0.f, 0.f, 0.f, 0.f};
    const float scale = 0.0625f;  // 1/sqrt(256)

    for (int s0 = s_beg; s0 < s_beg + 1024; s0 += 64) {
        float acc[4][4];
        #pragma unroll
        for (int i = 0; i < 4; i++)
            #pragma unroll
            for (int j = 0; j < 4; j++) acc[i][j] = 0.f;

        for (int d0 = 0; d0 < CC; d0 += 16) {
            int nn = t & 63, cc0 = t >> 6;
            #pragma unroll
            for (int r = 0; r < 4; r++) {
                int cc = cc0 + 4 * r;
                lq[cc][nn] = Q[(size_t)(d0 + cc) * HWN + q0 + nn];
                lk[cc][nn] = K[(size_t)(d0 + cc) * HWN + s0 + nn];
            }
            __syncthreads();
            #pragma unroll
            for (int cc = 0; cc < 16; cc++) {
                float4 qv4 = *(const float4*)&lq[cc][4 * ty];
                float4 kv4 = *(const float4*)&lk[cc][4 * tx];
                float qv[4] = {qv4.x, qv4.y, qv4.z, qv4.w};
                float kv[4] = {kv4.x, kv4.y, kv4.z, kv4.w};
                #pragma unroll
                for (int i = 0; i < 4; i++)
                    #pragma unroll
                    for (int j = 0; j < 4; j++)
                        acc[i][j] = fmaf(qv[i], kv[j], acc[i][j]);
            }
            __syncthreads();
        }

        float4 vx4 = *(const float4*)&fx[s0 + 4 * tx];
        float4 vy4 = *(const float4*)&fy[s0 + 4 * tx];
        float vx[4] = {vx4.x, vx4.y, vx4.z, vx4.w};
        float vy[4] = {vy4.x, vy4.y, vy4.z, vy4.w};
        #pragma unroll
        for (int i = 0; i < 4; i++) {
            #pragma unroll
            for (int j = 0; j < 4; j++) {
                float p = __expf(acc[i][j] * scale);
                den[i] += p;
                nx[i]  = fmaf(p, vx[j], nx[i]);
                ny[i]  = fmaf(p, vy[j], ny[i]);
            }
        }
    }

    // reduce across the 16 s-lanes (tx) within each 16-lane group
    #pragma unroll
    for (int i = 0; i < 4; i++) {
        #pragma unroll
        for (int off = 8; off >= 1; off >>= 1) {
            den[i] += __shfl_down(den[i], off, 16);
            nx[i]  += __shfl_down(nx[i],  off, 16);
            ny[i]  += __shfl_down(ny[i],  off, 16);
        }
    }
    if (tx == 0) {
        #pragma unroll
        for (int i = 0; i < 4; i++) {
            int qidx = b * HWN + q0 + 4 * ty + i;
            atomicAdd(&den_g[qidx], den[i]);
            atomicAdd(&nx_g[qidx],  nx[i]);
            atomicAdd(&ny_g[qidx],  ny[i]);
        }
    }
}

// ---------------------------------------------------------------------------
// Finalize: out[b][v][n] = num_v[b][n] / den[b][n]
// ---------------------------------------------------------------------------
__global__ __launch_bounds__(256) void finalize_kernel(
    const float* __restrict__ den_g, const float* __restrict__ nx_g,
    const float* __restrict__ ny_g, float* __restrict__ out)
{
    int idx = blockIdx.x * 256 + threadIdx.x;  // 0 .. 4*4096-1 = b*HW + n
    int b = idx >> 12, n = idx & 4095;
    float inv = 1.0f / den_g[idx];
    out[(size_t)b * 2 * HWN + n]       = nx_g[idx] * inv;
    out[(size_t)b * 2 * HWN + HWN + n] = ny_g[idx] * inv;
}

extern "C" void kernel_launch(void* const* d_in, const int* in_sizes, int n_in,
                              void* d_out, int out_size, void* d_ws, size_t ws_size,
                              hipStream_t stream) {
    const float* feature = (const float*)d_in[0];
    const float* flow    = (const float*)d_in[1];
    const float* q_w     = (const float*)d_in[2];
    const float* q_b     = (const float*)d_in[3];
    const float* k_w     = (const float*)d_in[4];
    const float* k_b     = (const float*)d_in[5];
    float* out = (float*)d_out;

    float* qt  = (float*)d_ws;                     // [B][C][HW]
    float* kt  = qt + (size_t)BB * CC * HWN;       // [B][C][HW]
    float* den = kt + (size_t)BB * CC * HWN;       // [B][HW]
    float* nx  = den + (size_t)BB * HWN;
    float* ny  = nx + (size_t)BB * HWN;

    hipMemsetAsync(den, 0, (size_t)3 * BB * HWN * sizeof(float), stream);
    proj_kernel<<<2048, 256, 0, stream>>>(feature, q_w, q_b, k_w, k_b, qt, kt);
    attn_kernel<<<1024, 256, 0, stream>>>(qt, kt, flow, den, nx, ny);
    finalize_kernel<<<64, 256, 0, stream>>>(den, nx, ny, out);
}

// Round 2
// 254.534 us; speedup vs baseline: 2.5502x; 2.5502x over previous
//
#include <hip/hip_runtime.h>
#include <math.h>

#define BB 4
#define CC 256
#define HWN 4096

typedef __attribute__((ext_vector_type(8))) short short8;
typedef __attribute__((ext_vector_type(4))) float f32x4;
typedef unsigned short ushort_t;

__device__ __forceinline__ ushort_t f2bf(float f) {
    unsigned int u = __float_as_uint(f);
    unsigned int r = (u + 0x7FFFu + ((u >> 16) & 1u)) >> 16;   // RNE
    return (ushort_t)r;
}

// ---------------------------------------------------------------------------
// Projection (fp32 compute, full precision): writes bf16 token-major
// Qb[b][n][d], Kb[b][n][d] — the MFMA-fragment-friendly layout.
// ---------------------------------------------------------------------------
__global__ __launch_bounds__(256) void proj_kernel(
    const float* __restrict__ feature,
    const float* __restrict__ q_w, const float* __restrict__ q_b,
    const float* __restrict__ k_w, const float* __restrict__ k_b,
    ushort_t* __restrict__ qb, ushort_t* __restrict__ kb)
{
    int id = blockIdx.x;
    int dtile = id & 3;  id >>= 2;
    int ntile = id & 63; id >>= 6;
    int which = id & 1;  id >>= 1;
    int b = id;

    const float* w    = which ? k_w : q_w;
    const float* bias = which ? k_b : q_b;
    ushort_t* outp    = which ? kb  : qb;

    int n0 = ntile * 64, d0 = dtile * 64;
    const float* F = feature + (size_t)b * CC * HWN;

    __shared__ __align__(16) float lw[16][68];  // [c][d]
    __shared__ __align__(16) float lf[16][68];  // [c][n]

    int t  = threadIdx.x;
    int tx = t & 15, ty = t >> 4;

    float acc[4][4];
    #pragma unroll
    for (int i = 0; i < 4; i++)
        #pragma unroll
        for (int j = 0; j < 4; j++) acc[i][j] = 0.f;

    for (int c0 = 0; c0 < CC; c0 += 16) {
        {
            int cc = t & 15, dd0 = t >> 4;
            #pragma unroll
            for (int r = 0; r < 4; r++) {
                int dd = dd0 + 16 * r;
                lw[cc][dd] = w[(size_t)(d0 + dd) * CC + c0 + cc];
            }
        }
        {
            int nn = t & 63, cc0 = t >> 6;
            #pragma unroll
            for (int r = 0; r < 4; r++) {
                int cc = cc0 + 4 * r;
                lf[cc][nn] = F[(size_t)(c0 + cc) * HWN + n0 + nn];
            }
        }
        __syncthreads();
        #pragma unroll
        for (int cc = 0; cc < 16; cc++) {
            float4 wv4 = *(const float4*)&lw[cc][4 * ty];
            float4 fv4 = *(const float4*)&lf[cc][4 * tx];
            float wv[4] = {wv4.x, wv4.y, wv4.z, wv4.w};
            float fv[4] = {fv4.x, fv4.y, fv4.z, fv4.w};
            #pragma unroll
            for (int i = 0; i < 4; i++)
                #pragma unroll
                for (int j = 0; j < 4; j++)
                    acc[i][j] = fmaf(wv[i], fv[j], acc[i][j]);
        }
        __syncthreads();
    }

    float b4[4];
    #pragma unroll
    for (int i = 0; i < 4; i++) b4[i] = bias[d0 + 4 * ty + i];

    ushort_t* ob = outp + (size_t)b * HWN * CC;
    #pragma unroll
    for (int j = 0; j < 4; j++) {
        ushort4 h;
        h.x = f2bf(acc[0][j] + b4[0]);
        h.y = f2bf(acc[1][j] + b4[1]);
        h.z = f2bf(acc[2][j] + b4[2]);
        h.w = f2bf(acc[3][j] + b4[3]);
        *(ushort4*)&ob[(size_t)(n0 + 4 * tx + j) * CC + d0 + 4 * ty] = h;
    }
}

// ---------------------------------------------------------------------------
// MFMA attention: block = (b, 128-q tile, 1024-key range); 4 waves x 32 q.
// Per wave: Q frags resident in registers (2 A-tiles x 8 d-chunks), 16-key
// s-tiles with register-double-buffered K frags, 16 MFMAs/tile, exp epilogue.
// No-max softmax => s-range split is additively exact via atomics.
// ---------------------------------------------------------------------------
__global__ __launch_bounds__(256) void attn_kernel(
    const ushort_t* __restrict__ qb, const ushort_t* __restrict__ kb,
    const float* __restrict__ flow,
    float* __restrict__ den_g, float* __restrict__ nx_g, float* __restrict__ ny_g)
{
    int id = blockIdx.x;
    int sr = id & 3;  id >>= 2;
    int qt = id & 31; id >>= 5;
    int b = id;

    int w    = threadIdx.x >> 6;
    int lane = threadIdx.x & 63;
    int n16  = lane & 15;
    int quad = lane >> 4;

    int q0    = qt * 128 + w * 32;
    int s_beg = sr * 1024;
    int s_end = s_beg + 1024;

    const ushort_t* Qb = qb + (size_t)b * HWN * CC;
    const ushort_t* Kb = kb + (size_t)b * HWN * CC;
    const float* fx = flow + (size_t)b * 2 * HWN;
    const float* fy = fx + HWN;

    // Q fragments: A[m=lane&15][k=quad*8+j], 2 tiles x 8 d-chunks
    short8 qf[2][8];
    #pragma unroll
    for (int tq = 0; tq < 2; tq++)
        #pragma unroll
        for (int c = 0; c < 8; c++)
            qf[tq][c] = *(const short8*)&Qb[(size_t)(q0 + tq * 16 + n16) * CC
                                            + c * 32 + quad * 8];

    float den[2][4], nxa[2][4], nya[2][4];
    #pragma unroll
    for (int tq = 0; tq < 2; tq++)
        #pragma unroll
        for (int r = 0; r < 4; r++) { den[tq][r] = 0.f; nxa[tq][r] = 0.f; nya[tq][r] = 0.f; }

    const float scale = 0.0625f;  // 1/sqrt(256)

    short8 kf[8], kf2[8];
    #pragma unroll
    for (int c = 0; c < 8; c++)
        kf[c] = *(const short8*)&Kb[(size_t)(s_beg + n16) * CC + c * 32 + quad * 8];

    for (int s0 = s_beg; s0 < s_end; s0 += 16) {
        int sp = (s0 + 16 < s_end) ? (s0 + 16) : s_beg;  // uniform, in-bounds
        #pragma unroll
        for (int c = 0; c < 8; c++)
            kf2[c] = *(const short8*)&Kb[(size_t)(sp + n16) * CC + c * 32 + quad * 8];

        f32x4 acc0 = {0.f, 0.f, 0.f, 0.f};
        f32x4 acc1 = {0.f, 0.f, 0.f, 0.f};
        #pragma unroll
        for (int c = 0; c < 8; c++) {
            acc0 = __builtin_amdgcn_mfma_f32_16x16x32_bf16(qf[0][c], kf[c], acc0, 0, 0, 0);
            acc1 = __builtin_amdgcn_mfma_f32_16x16x32_bf16(qf[1][c], kf[c], acc1, 0, 0, 0);
        }

        float vx = fx[s0 + n16];
        float vy = fy[s0 + n16];
        #pragma unroll
        for (int r = 0; r < 4; r++) {
            float p0 = __expf(acc0[r] * scale);
            float p1 = __expf(acc1[r] * scale);
            den[0][r] += p0;            den[1][r] += p1;
            nxa[0][r] = fmaf(p0, vx, nxa[0][r]);  nxa[1][r] = fmaf(p1, vx, nxa[1][r]);
            nya[0][r] = fmaf(p0, vy, nya[0][r]);  nya[1][r] = fmaf(p1, vy, nya[1][r]);
        }

        #pragma unroll
        for (int c = 0; c < 8; c++) kf[c] = kf2[c];
    }

    // reduce across the 16 s-lanes within each quad
    #pragma unroll
    for (int tq = 0; tq < 2; tq++)
        #pragma unroll
        for (int r = 0; r < 4; r++) {
            #pragma unroll
            for (int off = 8; off >= 1; off >>= 1) {
                den[tq][r] += __shfl_down(den[tq][r], off, 16);
                nxa[tq][r] += __shfl_down(nxa[tq][r], off, 16);
                nya[tq][r] += __shfl_down(nya[tq][r], off, 16);
            }
        }
    if (n16 == 0) {
        #pragma unroll
        for (int tq = 0; tq < 2; tq++)
            #pragma unroll
            for (int r = 0; r < 4; r++) {
                int qrow = q0 + tq * 16 + quad * 4 + r;
                int gi = b * HWN + qrow;
                atomicAdd(&den_g[gi], den[tq][r]);
                atomicAdd(&nx_g[gi],  nxa[tq][r]);
                atomicAdd(&ny_g[gi],  nya[tq][r]);
            }
    }
}

// ---------------------------------------------------------------------------
__global__ __launch_bounds__(256) void finalize_kernel(
    const float* __restrict__ den_g, const float* __restrict__ nx_g,
    const float* __restrict__ ny_g, float* __restrict__ out)
{
    int idx = blockIdx.x * 256 + threadIdx.x;  // b*HW + n
    int b = idx >> 12, n = idx & 4095;
    float inv = 1.0f / den_g[idx];
    out[(size_t)b * 2 * HWN + n]       = nx_g[idx] * inv;
    out[(size_t)b * 2 * HWN + HWN + n] = ny_g[idx] * inv;
}

extern "C" void kernel_launch(void* const* d_in, const int* in_sizes, int n_in,
                              void* d_out, int out_size, void* d_ws, size_t ws_size,
                              hipStream_t stream) {
    const float* feature = (const float*)d_in[0];
    const float* flow    = (const float*)d_in[1];
    const float* q_w     = (const float*)d_in[2];
    const float* q_b     = (const float*)d_in[3];
    const float* k_w     = (const float*)d_in[4];
    const float* k_b     = (const float*)d_in[5];
    float* out = (float*)d_out;

    ushort_t* qb = (ushort_t*)d_ws;                         // [B][HW][C] bf16
    ushort_t* kb = qb + (size_t)BB * HWN * CC;              // [B][HW][C] bf16
    float* den = (float*)(kb + (size_t)BB * HWN * CC);      // [B][HW]
    float* nx  = den + (size_t)BB * HWN;
    float* ny  = nx + (size_t)BB * HWN;

    hipMemsetAsync(den, 0, (size_t)3 * BB * HWN * sizeof(float), stream);
    proj_kernel<<<2048, 256, 0, stream>>>(feature, q_w, q_b, k_w, k_b, qb, kb);
    attn_kernel<<<512, 256, 0, stream>>>(qb, kb, flow, den, nx, ny);
    finalize_kernel<<<64, 256, 0, stream>>>(den, nx, ny, out);
}